// Round 12
// baseline (646.406 us; speedup 1.0000x reference)
//
#include <hip/hip_runtime.h>

#define L1_BINS 4096          // top 12 bits of 22-bit fixed-point key
#define L1_UINTS 2048         // packed pairs (16-bit counts)
#define L2_BINS 1024          // low 10 bits
#define KEY_MAX 4194303u      // 2^22 - 1
#define NH2_BLOCKS 2048
#define NMG_BLOCKS 256
#define NREF_BLOCKS 2048
#define NBIN_BLOCKS 2048

struct Ranks { unsigned int r[32]; };
struct Fracs { float f[16]; };

__device__ __forceinline__ unsigned int wave_iscan(unsigned int s, int lane) {
  unsigned int inc = s;
#pragma unroll
  for (int d = 1; d < 64; d <<= 1) {
    unsigned int u = __shfl_up(inc, d);
    if (lane >= d) inc += u;
  }
  return inc;
}

// ---------------- Kernel 1: 4 lanes/row coalesced; 8KB packed LDS hist -----
__global__ __launch_bounds__(256) void k_h2(const float4* __restrict__ lg4,
                                            const int* __restrict__ labels,
                                            unsigned int* __restrict__ keys,
                                            unsigned int* __restrict__ histg,
                                            unsigned int* __restrict__ dones,
                                            int n) {
  __shared__ unsigned int lh[L1_UINTS];
  for (int i = threadIdx.x; i < L1_UINTS; i += 256) lh[i] = 0u;
  if (blockIdx.x == 0 && threadIdx.x < 3) dones[threadIdx.x] = 0u;
  __syncthreads();
  int tid = blockIdx.x * 256 + threadIdx.x;
  int sub = tid & 3;
  int group = tid >> 2;
  int ngroups = (gridDim.x * 256) >> 2;
  for (int row = group; row < n; row += ngroups) {
    float4 v = lg4[(size_t)row * 4 + sub];
    float m = v.x; int a = 0;
    if (v.y > m) { m = v.y; a = 1; }
    if (v.z > m) { m = v.z; a = 2; }
    if (v.w > m) { m = v.w; a = 3; }
    int gidx = sub * 4 + a;
#pragma unroll
    for (int mask = 1; mask <= 2; mask <<= 1) {
      float om = __shfl_xor(m, mask);
      int oi = __shfl_xor(gidx, mask);
      if (om > m || (om == m && oi < gidx)) { m = om; gidx = oi; }
    }
    float e0 = __expf(v.x - m), e1 = __expf(v.y - m);
    float e2 = __expf(v.z - m), e3 = __expf(v.w - m);
    float Z = e0 + e1 + e2 + e3;
    float S2 = e0 * e0 + e1 * e1 + e2 * e2 + e3 * e3;
#pragma unroll
    for (int mask = 1; mask <= 2; mask <<= 1) {
      Z += __shfl_xor(Z, mask);
      S2 += __shfl_xor(S2, mask);
    }
    if (sub == 0) {
      float r = S2 / (Z * Z) + 1e-12f;
      float h2 = -__log2f(r);
      int ki = (int)(h2 * 1048576.0f);
      unsigned int key = (unsigned int)min(max(ki, 0), (int)KEY_MAX);
      keys[row] = key | ((gidx != labels[row]) ? 0x80000000u : 0u);
      atomicAdd(&lh[key >> 11], ((key >> 10) & 1u) ? 65536u : 1u);
    }
  }
  __syncthreads();
  unsigned int* dst = histg + (size_t)blockIdx.x * L1_UINTS;
  for (int i = threadIdx.x; i < L1_UINTS; i += 256) dst[i] = lh[i];
}

// ---------------- Kernel 2: merge hists; last block does select-L1 ---------
__global__ __launch_bounds__(256) void k_merge(const unsigned int* __restrict__ histg,
                                               unsigned int* __restrict__ merged,
                                               unsigned int* __restrict__ hist2,
                                               unsigned int* __restrict__ dones,
                                               unsigned int* __restrict__ selpfx,
                                               unsigned int* __restrict__ selrank,
                                               Ranks rk) {
  __shared__ unsigned int slo[32][9], shi[32][9];
  __shared__ unsigned int is_last;
  for (int i = threadIdx.x; i < 128; i += 256)
    hist2[blockIdx.x * 128 + i] = 0u;
  int col0 = blockIdx.x * 8;
  int c = threadIdx.x & 7;
  int rg = threadIdx.x >> 3;
  unsigned int alo = 0, ahi = 0;
  for (int r = rg; r < NH2_BLOCKS; r += 32) {
    unsigned int v = histg[(size_t)r * L1_UINTS + col0 + c];
    alo += v & 0xFFFFu;
    ahi += v >> 16;
  }
  slo[rg][c] = alo;
  shi[rg][c] = ahi;
  __syncthreads();
  if (threadIdx.x < 8) {
    unsigned int lo = 0, hi = 0;
#pragma unroll
    for (int g = 0; g < 32; ++g) { lo += slo[g][threadIdx.x]; hi += shi[g][threadIdx.x]; }
    int pc = col0 + threadIdx.x;
    merged[2 * pc] = lo;
    merged[2 * pc + 1] = hi;
  }
  __threadfence();
  __syncthreads();
  if (threadIdx.x == 0)
    is_last = (atomicAdd(&dones[0], 1u) == (unsigned int)gridDim.x - 1u) ? 1u : 0u;
  __syncthreads();
  if (!is_last) return;
  __threadfence();
  int wid = threadIdx.x >> 6, lane = threadIdx.x & 63;
  for (int j = wid; j < 32; j += 4) {
    unsigned int rem = rk.r[j];
    const unsigned int* mp = merged + lane * 64;
    unsigned int s = 0;
#pragma unroll 8
    for (int t = 0; t < 64; ++t) s += mp[t];
    unsigned int inc = wave_iscan(s, lane);
    unsigned int ex = inc - s;
    bool own = (rem >= ex) && (rem < ex + s);
    int src = __ffsll((long long)__ballot(own)) - 1;
    rem -= __shfl(ex, src);
    int base = src * 64;
    unsigned int v2 = merged[base + lane];
    unsigned int inc2 = wave_iscan(v2, lane);
    unsigned int ex2 = inc2 - v2;
    bool own2 = (rem >= ex2) && (rem < ex2 + v2);
    int s2 = __ffsll((long long)__ballot(own2)) - 1;
    unsigned int ex2s = __shfl(ex2, s2);
    if (lane == 0) {
      selpfx[j] = (unsigned int)(base + s2);
      selrank[j] = rem - ex2s;
    }
  }
}

// ---------------- Kernel 3: refine via LDS bin-map (uint4 loads) -----------
__global__ __launch_bounds__(256) void k_refine(const unsigned int* __restrict__ keys,
                                                const unsigned int* __restrict__ selpfx,
                                                unsigned int* __restrict__ hist2,
                                                unsigned int* __restrict__ dones,
                                                unsigned int* __restrict__ selrank,
                                                unsigned int* __restrict__ vout,
                                                int n) {
  __shared__ unsigned char selmap[L1_BINS];
  __shared__ unsigned int sp[32];
  __shared__ unsigned int is_last;
  for (int i = threadIdx.x; i < L1_BINS; i += 256) selmap[i] = 0xFF;
  if (threadIdx.x < 32) sp[threadIdx.x] = selpfx[threadIdx.x];
  __syncthreads();
  if (threadIdx.x == 0) {
    for (int j = 31; j >= 0; --j) selmap[sp[j]] = (unsigned char)j;  // lowest j wins
  }
  __syncthreads();
  int n4 = n >> 2;
  int stride = gridDim.x * blockDim.x;
  const uint4* k4 = reinterpret_cast<const uint4*>(keys);
  for (int i = blockIdx.x * blockDim.x + threadIdx.x; i < n4; i += stride) {
    uint4 kv = k4[i];
#define REF1(KK) { unsigned int key = (KK) & KEY_MAX; unsigned int c = selmap[key >> 10]; \
    if (c != 0xFFu) atomicAdd(&hist2[(int)c * L2_BINS + (int)(key & (L2_BINS - 1))], 1u); }
    REF1(kv.x) REF1(kv.y) REF1(kv.z) REF1(kv.w)
#undef REF1
  }
  // tail (n not multiple of 4)
  if (blockIdx.x == 0 && threadIdx.x < (n & 3)) {
    unsigned int key = keys[(n4 << 2) + threadIdx.x] & KEY_MAX;
    unsigned int c = selmap[key >> 10];
    if (c != 0xFFu) atomicAdd(&hist2[(int)c * L2_BINS + (int)(key & (L2_BINS - 1))], 1u);
  }
  __threadfence();
  __syncthreads();
  if (threadIdx.x == 0)
    is_last = (atomicAdd(&dones[1], 1u) == (unsigned int)gridDim.x - 1u) ? 1u : 0u;
  __syncthreads();
  if (!is_last) return;
  __threadfence();
  int wid = threadIdx.x >> 6, lane = threadIdx.x & 63;
  for (int j = wid; j < 32; j += 4) {
    unsigned int rem = selrank[j];
    unsigned int canon = selmap[sp[j]];
    const unsigned int* h = hist2 + (int)canon * L2_BINS;
    unsigned int s = 0;
#pragma unroll
    for (int t = 0; t < 16; ++t) s += h[lane * 16 + t];
    unsigned int inc = wave_iscan(s, lane);
    unsigned int ex = inc - s;
    bool own = (rem >= ex) && (rem < ex + s);
    int src = __ffsll((long long)__ballot(own)) - 1;
    rem -= __shfl(ex, src);
    unsigned int v2 = (lane < 16) ? h[src * 16 + lane] : 0u;
    unsigned int inc2 = wave_iscan(v2, lane);
    unsigned int ex2 = inc2 - v2;
    bool own2 = (lane < 16) && (rem >= ex2) && (rem < ex2 + v2);
    int s2 = __ffsll((long long)__ballot(own2)) - 1;
    if (lane == 0)
      vout[j] = (sp[j] << 10) | (unsigned int)(src * 16 + s2);  // 22-bit key
  }
}

// ---------------- Kernel 4: wave ballot/shuffle binning (no accumulators) --
// partials: [v][block], v = bin*4+{0=cnt,1=err,2=kk_lo32,3=kk_hi32}
__global__ __launch_bounds__(256) void k_bin(const unsigned int* __restrict__ keys,
                                             const unsigned int* __restrict__ vp,
                                             unsigned int* __restrict__ partials,
                                             unsigned int* __restrict__ dones,
                                             float* __restrict__ out, int n,
                                             Fracs fr) {
  __shared__ unsigned int sT[16];
  __shared__ unsigned int blkCE[15];
  __shared__ unsigned long long blkKK[15];
  __shared__ double dacc[60];
  __shared__ unsigned int is_last;
  if (threadIdx.x < 16) {
    int i = threadIdx.x;
    float lo = (float)(vp[2 * i] + 1u) * 0x1p-20f;   // exact
    float hi = (float)(vp[2 * i + 1] + 1u) * 0x1p-20f;
    float f = fr.f[i];
    float e = lo * (1.0f - f) + hi * f;
    if (i == 15) e += 1e-6f;
    // T = smallest key with (key+0.5)*2^-20 > e
    double kd = (double)e * 1048576.0 - 0.5;
    int T = (int)floor(kd) + 1;
    while (T > 0 && ((float)(T - 1) + 0.5f) * 0x1p-20f > e) --T;
    while (((float)T + 0.5f) * 0x1p-20f <= e) ++T;
    sT[i] = (unsigned int)T;
  }
  if (threadIdx.x >= 64 && threadIdx.x < 79) blkCE[threadIdx.x - 64] = 0u;
  if (threadIdx.x >= 128 && threadIdx.x < 143) blkKK[threadIdx.x - 128] = 0ull;
  __syncthreads();
  unsigned int tT[16];
#pragma unroll
  for (int j = 0; j < 16; ++j) tT[j] = sT[j];
  int lane = threadIdx.x & 63;
  int stride = gridDim.x * 256;
  // pad so every lane of a wave runs the same trip count (ballot-safe)
  int npad = ((n + stride - 1) / stride) * stride;
  for (int i = blockIdx.x * 256 + threadIdx.x; i < npad; i += stride) {
    bool valid = (i < n);
    unsigned int kp = valid ? keys[i] : 0u;
    unsigned int key = kp & KEY_MAX;
    unsigned int er = kp >> 31;
    int less = 0;
#pragma unroll
    for (int j = 0; j < 16; ++j) less += (key >= tT[j]) ? 1 : 0;
    int bin = valid ? (less - 1) : -1;  // valid bins 0..14
#pragma unroll
    for (int b = 0; b < 15; ++b) {
      unsigned long long mb = __ballot(bin == b);
      if (mb == 0ull) continue;
      unsigned int cnt = (unsigned int)__popcll(mb);
      unsigned int erc = (unsigned int)__popcll(__ballot((bin == b) && er));
      unsigned int kv = (bin == b) ? key : 0u;
#pragma unroll
      for (int off = 32; off > 0; off >>= 1) kv += __shfl_xor(kv, off);
      if (lane == 0) {
        atomicAdd(&blkCE[b], cnt | (erc << 16));
        atomicAdd(&blkKK[b], (unsigned long long)kv);
      }
    }
  }
  __syncthreads();
  if (threadIdx.x < 60) {
    int b = threadIdx.x >> 2, comp = threadIdx.x & 3;
    unsigned int ce = blkCE[b];
    unsigned long long kk = blkKK[b];
    unsigned int v = (comp == 0) ? (ce & 0xFFFFu)
                   : (comp == 1) ? (ce >> 16)
                   : (comp == 2) ? (unsigned int)(kk & 0xFFFFFFFFull)
                                 : (unsigned int)(kk >> 32);
    partials[threadIdx.x * NBIN_BLOCKS + blockIdx.x] = v;
  }
  __threadfence();
  __syncthreads();
  if (threadIdx.x == 0)
    is_last = (atomicAdd(&dones[2], 1u) == (unsigned int)gridDim.x - 1u) ? 1u : 0u;
  __syncthreads();
  if (!is_last) return;
  __threadfence();
  int wid = threadIdx.x >> 6;
  for (int v = wid; v < 60; v += 4) {
    double s = 0.0;
    const unsigned int* pv = partials + v * NBIN_BLOCKS;
    for (int b2 = lane; b2 < NBIN_BLOCKS; b2 += 64) s += (double)pv[b2];
    for (int off = 32; off > 0; off >>= 1) s += __shfl_xor(s, off);
    if (lane == 0) dacc[v] = s;
  }
  __syncthreads();
  if (threadIdx.x == 0) {
    float g = 0.f;
    for (int b = 0; b < 15; ++b) {
      double cd = dacc[b * 4 + 0];
      double ed = dacc[b * 4 + 1];
      double kd = dacc[b * 4 + 3] * 4294967296.0 + dacc[b * 4 + 2];
      double safe = cd > 1.0 ? cd : 1.0;
      float u = (float)(((kd + 0.5 * cd) * (1.0 / 1048576.0)) / safe);
      float eb = (float)(ed / safe);
      float inner = 2.0f * exp2f(-u) - 1.0f;
      float s = (inner > 0.f) ? sqrtf(inner) : 0.f;
      float risk = 0.5f * (1.0f - s);
      g += (cd > 0.0) ? fabsf(eb - risk) : 0.f;
    }
    out[0] = g * (1.0f / 15.0f);
  }
}

extern "C" void kernel_launch(void* const* d_in, const int* in_sizes, int n_in,
                              void* d_out, int out_size, void* d_ws, size_t ws_size,
                              hipStream_t stream) {
  const float* logits = (const float*)d_in[0];
  const int* labels = (const int*)d_in[1];
  float* out = (float*)d_out;
  int n = in_sizes[1];  // labels count = number of rows

  char* ws = (char*)d_ws;
  size_t offKeys = 0;                                             // n*4 = 16MB
  size_t offHg = (size_t)n * 4;                                   // 2048*2048*4 = 16MB
  size_t offMerged = offHg + (size_t)NH2_BLOCKS * L1_UINTS * 4;   // 4096*4
  size_t offH2b = offMerged + (size_t)L1_BINS * 4;                // 32*1024*4
  size_t offDone = offH2b + (size_t)32 * L2_BINS * 4;             // 16B
  size_t offSelP = offDone + 16;                                  // 32*4
  size_t offSelR = offSelP + 128;                                 // 32*4
  size_t offV = offSelR + 128;                                    // 32*4
  size_t offPart = (offV + 128 + 255) & ~(size_t)255;             // 60*NBIN_BLOCKS*4

  unsigned int* keys = (unsigned int*)(ws + offKeys);
  unsigned int* histg = (unsigned int*)(ws + offHg);
  unsigned int* merged = (unsigned int*)(ws + offMerged);
  unsigned int* hist2 = (unsigned int*)(ws + offH2b);
  unsigned int* dones = (unsigned int*)(ws + offDone);
  unsigned int* selp = (unsigned int*)(ws + offSelP);
  unsigned int* selr = (unsigned int*)(ws + offSelR);
  unsigned int* vp = (unsigned int*)(ws + offV);
  unsigned int* part = (unsigned int*)(ws + offPart);

  // host-side quantile positions (f32, matching jnp.linspace/quantile math)
  Ranks rk;
  Fracs fr;
  float nm1 = (float)(n - 1);
  for (int i = 0; i < 16; ++i) {
    float q = (i == 15) ? 1.0f : (float)i * (1.0f / 15.0f);
    float idxf = q * nm1;
    float flo = floorf(idxf);
    unsigned int klo = (unsigned int)flo;
    unsigned int khi = (unsigned int)ceilf(idxf);
    unsigned int maxi = (unsigned int)(n - 1);
    if (klo > maxi) klo = maxi;
    if (khi > maxi) khi = maxi;
    rk.r[2 * i] = klo;
    rk.r[2 * i + 1] = khi;
    fr.f[i] = idxf - flo;
  }

  // 1) keys + per-block L1 hists (also zeroes done counters)
  k_h2<<<NH2_BLOCKS, 256, 0, stream>>>((const float4*)logits, labels, keys, histg, dones, n);
  // 2) merge hists; zero hist2; last block -> select L1 (12 bits)
  k_merge<<<NMG_BLOCKS, 256, 0, stream>>>(histg, merged, hist2, dones, selp, selr, rk);
  // 3) refine low 10 bits via LDS bin-map (uint4); last block -> select L2
  k_refine<<<NREF_BLOCKS, 256, 0, stream>>>(keys, selp, hist2, dones, selr, vp, n);
  // 4) wave ballot/shuffle binning + fused final
  k_bin<<<NBIN_BLOCKS, 256, 0, stream>>>(keys, vp, part, dones, out, n, fr);

  (void)n_in; (void)out_size; (void)ws_size;
}

// Round 13
// 320.969 us; speedup vs baseline: 2.0139x; 2.0139x over previous
//
#include <hip/hip_runtime.h>

#define L1_BINS 2048          // top 11 bits of 22-bit fixed-point key
#define L2_BINS 2048          // low 11 bits
#define KEY_MAX 4194303u      // 2^22 - 1
#define NH2_BLOCKS 1280       // 5 blocks/CU at 16KB LDS
#define NMG_BLOCKS 256
#define NREF_BLOCKS 2048

struct Ranks { unsigned int r[32]; };
struct Fracs { float f[16]; };

__device__ __forceinline__ unsigned int wave_iscan(unsigned int s, int lane) {
  unsigned int inc = s;
#pragma unroll
  for (int d = 1; d < 64; d <<= 1) {
    unsigned int u = __shfl_up(inc, d);
    if (lane >= d) inc += u;
  }
  return inc;
}

// ---- Kernel 1: keys + per-block L1 hist {cnt|err<<16, offsetsum} ---------
__global__ __launch_bounds__(256) void k_h2(const float4* __restrict__ lg4,
                                            const int* __restrict__ labels,
                                            unsigned int* __restrict__ keys,
                                            unsigned int* __restrict__ hce,
                                            unsigned int* __restrict__ hos,
                                            unsigned int* __restrict__ dones,
                                            int n) {
  __shared__ unsigned int lce[L1_BINS];
  __shared__ unsigned int los[L1_BINS];
  for (int i = threadIdx.x; i < L1_BINS; i += 256) { lce[i] = 0u; los[i] = 0u; }
  if (blockIdx.x == 0 && threadIdx.x < 3) dones[threadIdx.x] = 0u;
  __syncthreads();
  int tid = blockIdx.x * 256 + threadIdx.x;
  int sub = tid & 3;
  int group = tid >> 2;
  int ngroups = (gridDim.x * 256) >> 2;
  for (int row = group; row < n; row += ngroups) {
    float4 v = lg4[(size_t)row * 4 + sub];
    float m = v.x; int a = 0;
    if (v.y > m) { m = v.y; a = 1; }
    if (v.z > m) { m = v.z; a = 2; }
    if (v.w > m) { m = v.w; a = 3; }
    int gidx = sub * 4 + a;
#pragma unroll
    for (int mask = 1; mask <= 2; mask <<= 1) {
      float om = __shfl_xor(m, mask);
      int oi = __shfl_xor(gidx, mask);
      if (om > m || (om == m && oi < gidx)) { m = om; gidx = oi; }
    }
    float e0 = __expf(v.x - m), e1 = __expf(v.y - m);
    float e2 = __expf(v.z - m), e3 = __expf(v.w - m);
    float Z = e0 + e1 + e2 + e3;
    float S2 = e0 * e0 + e1 * e1 + e2 * e2 + e3 * e3;
#pragma unroll
    for (int mask = 1; mask <= 2; mask <<= 1) {
      Z += __shfl_xor(Z, mask);
      S2 += __shfl_xor(S2, mask);
    }
    if (sub == 0) {
      float r = S2 / (Z * Z) + 1e-12f;
      float h2 = -__log2f(r);
      int ki = (int)(h2 * 1048576.0f);
      unsigned int key = (unsigned int)min(max(ki, 0), (int)KEY_MAX);
      unsigned int er = (gidx != labels[row]) ? 1u : 0u;
      keys[row] = key | (er << 31);
      int b = key >> 11;
      atomicAdd(&lce[b], 1u | (er << 16));
      atomicAdd(&los[b], key & 2047u);
    }
  }
  __syncthreads();
  unsigned int* d1 = hce + (size_t)blockIdx.x * L1_BINS;
  unsigned int* d2 = hos + (size_t)blockIdx.x * L1_BINS;
  for (int i = threadIdx.x; i < L1_BINS; i += 256) { d1[i] = lce[i]; d2[i] = los[i]; }
}

// ---- Kernel 2: merge; zero hist2; last block: select-L1 ------------------
__global__ __launch_bounds__(256) void k_merge(const unsigned int* __restrict__ hce,
                                               const unsigned int* __restrict__ hos,
                                               unsigned int* __restrict__ g_cnt,
                                               unsigned int* __restrict__ g_err,
                                               unsigned long long* __restrict__ g_os,
                                               unsigned int* __restrict__ hist2,
                                               unsigned int* __restrict__ dones,
                                               unsigned int* __restrict__ selpfx,
                                               unsigned int* __restrict__ selrank,
                                               Ranks rk) {
  __shared__ unsigned int scnt[32][9], serr[32][9];
  __shared__ unsigned long long sos[32][9];
  __shared__ unsigned int is_last;
  // zero hist2 slice: 32*2048 u32 / 256 blocks = 256 each
  for (int i = threadIdx.x; i < 256; i += 256)
    hist2[blockIdx.x * 256 + i] = 0u;
  int col0 = blockIdx.x * 8;
  int c = threadIdx.x & 7;
  int rg = threadIdx.x >> 3;
  unsigned int acnt = 0, aerr = 0;
  unsigned long long aos = 0ull;
  for (int r = rg; r < NH2_BLOCKS; r += 32) {
    unsigned int v = hce[(size_t)r * L1_BINS + col0 + c];
    acnt += v & 0xFFFFu;
    aerr += v >> 16;
    aos += (unsigned long long)hos[(size_t)r * L1_BINS + col0 + c];
  }
  scnt[rg][c] = acnt; serr[rg][c] = aerr; sos[rg][c] = aos;
  __syncthreads();
  if (threadIdx.x < 8) {
    unsigned int tc = 0, te = 0;
    unsigned long long to = 0ull;
#pragma unroll
    for (int g = 0; g < 32; ++g) { tc += scnt[g][threadIdx.x]; te += serr[g][threadIdx.x]; to += sos[g][threadIdx.x]; }
    g_cnt[col0 + threadIdx.x] = tc;
    g_err[col0 + threadIdx.x] = te;
    g_os[col0 + threadIdx.x] = to;
  }
  __threadfence();
  __syncthreads();
  if (threadIdx.x == 0)
    is_last = (atomicAdd(&dones[0], 1u) == (unsigned int)gridDim.x - 1u) ? 1u : 0u;
  __syncthreads();
  if (!is_last) return;
  __threadfence();
  int wid = threadIdx.x >> 6, lane = threadIdx.x & 63;
  for (int j = wid; j < 32; j += 4) {
    unsigned int rem = rk.r[j];
    unsigned int s = 0;
#pragma unroll 8
    for (int t = 0; t < 32; ++t) s += g_cnt[lane * 32 + t];
    unsigned int inc = wave_iscan(s, lane);
    unsigned int ex = inc - s;
    bool own = (rem >= ex) && (rem < ex + s);
    int src = __ffsll((long long)__ballot(own)) - 1;
    rem -= __shfl(ex, src);
    unsigned int v2 = (lane < 32) ? g_cnt[src * 32 + lane] : 0u;
    unsigned int inc2 = wave_iscan(v2, lane);
    unsigned int ex2 = inc2 - v2;
    bool own2 = (lane < 32) && (rem >= ex2) && (rem < ex2 + v2);
    int s2 = __ffsll((long long)__ballot(own2)) - 1;
    unsigned int ex2s = __shfl(ex2, s2);
    if (lane == 0) {
      selpfx[j] = (unsigned int)(src * 32 + s2);
      selrank[j] = rem - ex2s;
    }
  }
}

// ---- Kernel 3: refine {cnt|err} per L2 slot; last block: select-L2 + FINAL
__global__ __launch_bounds__(256) void k_refine(const unsigned int* __restrict__ keys,
                                                const unsigned int* __restrict__ selpfx,
                                                unsigned int* __restrict__ hist2,
                                                unsigned int* __restrict__ dones,
                                                const unsigned int* __restrict__ selrank,
                                                const unsigned int* __restrict__ g_cnt,
                                                const unsigned int* __restrict__ g_err,
                                                const unsigned long long* __restrict__ g_os,
                                                float* __restrict__ out,
                                                int n, Fracs fr) {
  __shared__ unsigned char selmap[L1_BINS];
  __shared__ unsigned int sp[32];
  __shared__ unsigned int sv[32];
  __shared__ unsigned int sTT[16];
  __shared__ double SCa[16], SEa[16], SKa[16];
  __shared__ double red[3][4];
  __shared__ unsigned int is_last;
  for (int i = threadIdx.x; i < L1_BINS; i += 256) selmap[i] = 0xFF;
  if (threadIdx.x < 32) sp[threadIdx.x] = selpfx[threadIdx.x];
  __syncthreads();
  if (threadIdx.x == 0) {
    for (int j = 31; j >= 0; --j) selmap[sp[j]] = (unsigned char)j;  // lowest j wins
  }
  __syncthreads();
  int n4 = n >> 2;
  int stride = gridDim.x * blockDim.x;
  const uint4* k4 = reinterpret_cast<const uint4*>(keys);
  for (int i = blockIdx.x * blockDim.x + threadIdx.x; i < n4; i += stride) {
    uint4 kv = k4[i];
#define REF1(KK) { unsigned int kk = (KK); unsigned int key = kk & KEY_MAX;          \
    unsigned int c = selmap[key >> 11];                                               \
    if (c != 0xFFu) atomicAdd(&hist2[(int)c * L2_BINS + (int)(key & 2047u)],          \
                              1u | ((kk >> 31) << 16)); }
    REF1(kv.x) REF1(kv.y) REF1(kv.z) REF1(kv.w)
#undef REF1
  }
  if (blockIdx.x == 0 && threadIdx.x < (n & 3)) {
    unsigned int kk = keys[(n4 << 2) + threadIdx.x];
    unsigned int key = kk & KEY_MAX;
    unsigned int c = selmap[key >> 11];
    if (c != 0xFFu) atomicAdd(&hist2[(int)c * L2_BINS + (int)(key & 2047u)],
                              1u | ((kk >> 31) << 16));
  }
  __threadfence();
  __syncthreads();
  if (threadIdx.x == 0)
    is_last = (atomicAdd(&dones[1], 1u) == (unsigned int)gridDim.x - 1u) ? 1u : 0u;
  __syncthreads();
  if (!is_last) return;
  __threadfence();
  int wid = threadIdx.x >> 6, lane = threadIdx.x & 63;
  // ---- select-L2: 4 waves x 8 queries over 2048 slots (cnt = low 16) ----
  for (int j = wid; j < 32; j += 4) {
    unsigned int rem = selrank[j];
    unsigned int canon = selmap[sp[j]];
    const unsigned int* h = hist2 + (int)canon * L2_BINS;
    unsigned int s = 0;
#pragma unroll 8
    for (int t = 0; t < 32; ++t) s += h[lane * 32 + t] & 0xFFFFu;
    unsigned int inc = wave_iscan(s, lane);
    unsigned int ex = inc - s;
    bool own = (rem >= ex) && (rem < ex + s);
    int src = __ffsll((long long)__ballot(own)) - 1;
    rem -= __shfl(ex, src);
    unsigned int v2 = (lane < 32) ? (h[src * 32 + lane] & 0xFFFFu) : 0u;
    unsigned int inc2 = wave_iscan(v2, lane);
    unsigned int ex2 = inc2 - v2;
    bool own2 = (lane < 32) && (rem >= ex2) && (rem < ex2 + v2);
    int s2 = __ffsll((long long)__ballot(own2)) - 1;
    if (lane == 0) sv[j] = (sp[j] << 11) | (unsigned int)(src * 32 + s2);
  }
  __syncthreads();
  // ---- edges -> integer thresholds T[j] ----
  if (threadIdx.x < 16) {
    int i = threadIdx.x;
    float lo = (float)(sv[2 * i] + 1u) * 0x1p-20f;   // exact
    float hi = (float)(sv[2 * i + 1] + 1u) * 0x1p-20f;
    float f = fr.f[i];
    float e = lo * (1.0f - f) + hi * f;
    if (i == 15) e += 1e-6f;
    double kdd = (double)e * 1048576.0 - 0.5;
    int T = (int)floor(kdd) + 1;
    while (T > 0 && ((float)(T - 1) + 0.5f) * 0x1p-20f > e) --T;
    while (((float)T + 0.5f) * 0x1p-20f <= e) ++T;
    sTT[i] = (unsigned int)T;
  }
  __syncthreads();
  // ---- S(T) = sum over keys < T of {cnt, err, keysum} ----
  for (int j = 0; j < 16; ++j) {
    unsigned int T = sTT[j];
    int a1 = (int)(T >> 11);     // 0..2048
    int r = (int)(T & 2047u);
    double cd = 0.0, ed = 0.0, kd = 0.0;
    for (int i = threadIdx.x; i < a1; i += 256) {
      double c = (double)g_cnt[i];
      cd += c;
      ed += (double)g_err[i];
      kd += (double)((unsigned long long)i << 11) * c + (double)g_os[i];
    }
    if (a1 < L1_BINS && r > 0) {
      unsigned int canon = selmap[a1];
      if (canon != 0xFFu) {
        const unsigned int* h = hist2 + (int)canon * L2_BINS;
        double base = (double)((unsigned int)a1 << 11);
        for (int s0 = threadIdx.x; s0 < r; s0 += 256) {
          unsigned int ce = h[s0];
          double c = (double)(ce & 0xFFFFu);
          cd += c;
          ed += (double)(ce >> 16);
          kd += c * (base + (double)s0);
        }
      }
    }
    for (int off = 32; off > 0; off >>= 1) {
      cd += __shfl_xor(cd, off);
      ed += __shfl_xor(ed, off);
      kd += __shfl_xor(kd, off);
    }
    if (lane == 0) { red[0][wid] = cd; red[1][wid] = ed; red[2][wid] = kd; }
    __syncthreads();
    if (threadIdx.x == 0) {
      SCa[j] = red[0][0] + red[0][1] + red[0][2] + red[0][3];
      SEa[j] = red[1][0] + red[1][1] + red[1][2] + red[1][3];
      SKa[j] = red[2][0] + red[2][1] + red[2][2] + red[2][3];
    }
    __syncthreads();
  }
  if (threadIdx.x == 0) {
    float g = 0.f;
    for (int b = 0; b < 15; ++b) {
      double cd = SCa[b + 1] - SCa[b];
      double ed = SEa[b + 1] - SEa[b];
      double kd = SKa[b + 1] - SKa[b];
      double safe = cd > 1.0 ? cd : 1.0;
      float u = (float)(((kd + 0.5 * cd) * (1.0 / 1048576.0)) / safe);
      float eb = (float)(ed / safe);
      float inner = 2.0f * exp2f(-u) - 1.0f;
      float s = (inner > 0.f) ? sqrtf(inner) : 0.f;
      float risk = 0.5f * (1.0f - s);
      g += (cd > 0.0) ? fabsf(eb - risk) : 0.f;
    }
    out[0] = g * (1.0f / 15.0f);
  }
}

extern "C" void kernel_launch(void* const* d_in, const int* in_sizes, int n_in,
                              void* d_out, int out_size, void* d_ws, size_t ws_size,
                              hipStream_t stream) {
  const float* logits = (const float*)d_in[0];
  const int* labels = (const int*)d_in[1];
  float* out = (float*)d_out;
  int n = in_sizes[1];  // labels count = number of rows

  char* ws = (char*)d_ws;
  size_t offKeys = 0;                                              // n*4 = 16MB
  size_t offHce = (size_t)n * 4;                                   // 1280*2048*4 = 10MB
  size_t offHos = offHce + (size_t)NH2_BLOCKS * L1_BINS * 4;       // 10MB
  size_t offGcnt = offHos + (size_t)NH2_BLOCKS * L1_BINS * 4;      // 2048*4
  size_t offGerr = offGcnt + (size_t)L1_BINS * 4;                  // 2048*4
  size_t offGos = offGerr + (size_t)L1_BINS * 4;                   // 2048*8 (8B aligned)
  size_t offH2 = offGos + (size_t)L1_BINS * 8;                     // 32*2048*4 = 256KB
  size_t offDone = offH2 + (size_t)32 * L2_BINS * 4;               // 16B
  size_t offSelP = offDone + 16;                                   // 128
  size_t offSelR = offSelP + 128;                                  // 128

  unsigned int* keys = (unsigned int*)(ws + offKeys);
  unsigned int* hce = (unsigned int*)(ws + offHce);
  unsigned int* hos = (unsigned int*)(ws + offHos);
  unsigned int* g_cnt = (unsigned int*)(ws + offGcnt);
  unsigned int* g_err = (unsigned int*)(ws + offGerr);
  unsigned long long* g_os = (unsigned long long*)(ws + offGos);
  unsigned int* hist2 = (unsigned int*)(ws + offH2);
  unsigned int* dones = (unsigned int*)(ws + offDone);
  unsigned int* selp = (unsigned int*)(ws + offSelP);
  unsigned int* selr = (unsigned int*)(ws + offSelR);

  // host-side quantile positions (f32, matching jnp.linspace/quantile math)
  Ranks rk;
  Fracs fr;
  float nm1 = (float)(n - 1);
  for (int i = 0; i < 16; ++i) {
    float q = (i == 15) ? 1.0f : (float)i * (1.0f / 15.0f);
    float idxf = q * nm1;
    float flo = floorf(idxf);
    unsigned int klo = (unsigned int)flo;
    unsigned int khi = (unsigned int)ceilf(idxf);
    unsigned int maxi = (unsigned int)(n - 1);
    if (klo > maxi) klo = maxi;
    if (khi > maxi) khi = maxi;
    rk.r[2 * i] = klo;
    rk.r[2 * i + 1] = khi;
    fr.f[i] = idxf - flo;
  }

  // 1) keys + per-block L1 hists {cnt|err, offsetsum}; zero dones
  k_h2<<<NH2_BLOCKS, 256, 0, stream>>>((const float4*)logits, labels, keys, hce, hos, dones, n);
  // 2) merge -> g_cnt/g_err/g_os; zero hist2; last block: select-L1
  k_merge<<<NMG_BLOCKS, 256, 0, stream>>>(hce, hos, g_cnt, g_err, g_os, hist2, dones, selp, selr, rk);
  // 3) refine L2 {cnt|err}; last block: select-L2 + edges + range sums + out
  k_refine<<<NREF_BLOCKS, 256, 0, stream>>>(keys, selp, hist2, dones, selr, g_cnt, g_err, g_os, out, n, fr);

  (void)n_in; (void)out_size; (void)ws_size;
}